// Round 11
// baseline (1102.828 us; speedup 1.0000x reference)
//
#include <hip/hip_runtime.h>
#include <math.h>

#define MDIM   4096
#define NSTEPS 199
#define NBLK   256     // one block per CU
#define NTHR   1024    // 16 waves
#define B1C    0.9f
#define B2C    0.999f
#define EPSC   1e-8f

typedef unsigned long long u64;

// ---------------------------------------------------------------------------
// Prep: Qs[i][j] = 0.5*(va[i][j] + va[j][i]), LDS-tiled transpose (validated;
// r10 proved the fused in-kernel variant is NOT faster — keep this).
// ---------------------------------------------------------------------------
__global__ void prep_qs(const float* __restrict__ va, float* __restrict__ Qs) {
    __shared__ float tile[32][33];
    const int j0 = blockIdx.x * 32;
    const int i0 = blockIdx.y * 32;
    const int tx = threadIdx.x, ty = threadIdx.y;

    for (int k = 0; k < 32; k += 8)
        tile[ty + k][tx] = va[(size_t)(j0 + ty + k) * MDIM + i0 + tx];
    __syncthreads();
    for (int k = 0; k < 32; k += 8) {
        int i = i0 + ty + k;
        float a = va[(size_t)i * MDIM + j0 + tx];
        float b = tile[tx][ty + k];          // va[j][i]
        Qs[(size_t)i * MDIM + j0 + tx] = 0.5f * (a + b);
    }
}

// ---------------------------------------------------------------------------
// Init: u0 = 1 - mean; zero the two fan-out flag slabs (values are compared
// against t>=1, and parity slab t&1 only ever holds t or t-2, so 0 never
// aliases — no per-step slots needed).
// ---------------------------------------------------------------------------
__global__ void init_state(const float* __restrict__ mean,
                           float* __restrict__ u0,
                           int* __restrict__ fpriv, int nf) {
    int i = blockIdx.x * blockDim.x + threadIdx.x;
    if (i < MDIM) u0[i] = 1.0f - mean[i];
    if (i < nf)   fpriv[i] = 0;
}

// ---------------------------------------------------------------------------
// Persistent cooperative kernel — r3 champion compute + FAN-OUT flag sync.
//
// SYNC LEDGER (step µs): r3 flag+aggregator+go = 4.3 | flat polls 5.3-5.75 |
// counter RMW 6.4 | per-lane sparse on shared lines 6.6 | data-poll 7.7-14.5.
// Rules derived: readiness = contention-free STORES (no RMW); per-line
// request rate ≲256/round; barrier between flag observation and data load.
//
// Fan-out broadcast satisfies both rules AND removes the aggregator hop:
//   producer: u store -> B2 (per-wave vmcnt(0) drain; validated release
//             idiom) -> tid<256 stores fpriv[t&1][tid][bid] = t
//             (256 fire-and-forget 4B stores to 256 distinct lines).
//   consumer: wave 0 sweeps ITS OWN slab fpriv[t&1][bid][0..255] for ==t
//             (sole poller of those 8 lines, ~2 coalesced req/line/round)
//             -> B3 -> u load.
// Per consumer-line write rate: 256 stores/step = proven go-line rate.
// Correctness = r3's proof: flag follows drained u stores (RAW); all 256
// flags at t-1 imply every block consumed u_{t-2} (WAR for the double
// buffer); slab parity: value t overwrites t-2, stale never aliases.
// ---------------------------------------------------------------------------
__global__ __launch_bounds__(NTHR) void adam_persist(
        const float* __restrict__ Qs,
        float* u0, float* u1,
        const float* __restrict__ mean,
        float* __restrict__ w_out,
        int* __restrict__ fpriv) {
    __shared__ float pr[2][16][17];   // [buf][wave][local row], +1 pad

    const int tid  = threadIdx.x;
    const int bid  = blockIdx.x;
    const int wave = tid >> 6;
    const int lane = tid & 63;
    const int row  = bid * 16 + wave;
    const int col0 = wave * 256 + lane * 4;    // this lane's 4-element segment

    // ---- one-time: Q fragment -> registers (64 regs/lane) ----
    float4 qreg[16];
#pragma unroll
    for (int r = 0; r < 16; ++r)
        qreg[r] = *(const float4*)(Qs + (size_t)(bid * 16 + r) * MDIM + col0);

    float m = 0.0f, v = 0.0f, b1p = 1.0f, b2p = 1.0f;
    const float mrow = mean[row];
    float ucur = 1.0f - mrow;                  // u[row] lives in registers

    // ---- u_0 segment -> registers (agent atomics bypass stale caches) ----
    float uv0, uv1, uv2, uv3;
    {
        u64 d0 = __hip_atomic_load((const u64*)(u0 + col0),     __ATOMIC_RELAXED, __HIP_MEMORY_SCOPE_AGENT);
        u64 d1 = __hip_atomic_load((const u64*)(u0 + col0 + 2), __ATOMIC_RELAXED, __HIP_MEMORY_SCOPE_AGENT);
        uv0 = __uint_as_float((unsigned)d0);  uv1 = __uint_as_float((unsigned)(d0 >> 32));
        uv2 = __uint_as_float((unsigned)d1);  uv3 = __uint_as_float((unsigned)(d1 >> 32));
    }

    for (int t = 1; t <= NSTEPS; ++t) {
        float* uout = (t & 1) ? u1 : u0;       // u_t lands in buffer t&1
        const int b = t & 1;

        // ---- 16 row-partials over this lane's 4 columns ----
        float acc[16];
#pragma unroll
        for (int r = 0; r < 16; ++r) {
            float4 q = qreg[r];
            acc[r] = q.x * uv0 + q.y * uv1 + q.z * uv2 + q.w * uv3;
        }

        // ---- fold 16 values x 64 lanes -> 1 value/lane (30 shuffles) ----
#pragma unroll
        for (int stage = 0; stage < 4; ++stage) {
            const int mask = 32 >> stage;
            const int half = 8 >> stage;
            const bool hi = (lane & mask) != 0;
#pragma unroll
            for (int i = 0; i < half; ++i) {
                float plo = __shfl_xor(acc[i],        mask);
                float phi = __shfl_xor(acc[i + half], mask);
                acc[i] = hi ? (acc[i + half] + phi) : (acc[i] + plo);
            }
        }
        float acc0 = acc[0];
        acc0 += __shfl_xor(acc0, 1);   // finish sum within the quad
        acc0 += __shfl_xor(acc0, 2);

        if ((lane & 3) == 0) pr[b][wave][lane >> 2] = acc0;
        __syncthreads();               // B1: pr matrix ready

        // ---- cross-wave fold: wave w reduces local row w; Adam in regs ----
        float unew = ucur;
        if (lane < 16) {
            float p = pr[b][lane][wave];
            p += __shfl_xor(p, 1);
            p += __shfl_xor(p, 2);
            p += __shfl_xor(p, 4);
            p += __shfl_xor(p, 8);
            const float g = p;

            b1p *= B1C;
            b2p *= B2C;
            m = B1C * m + (1.0f - B1C) * g;
            v = B2C * v + (1.0f - B2C) * g * g;
            const float denom = sqrtf(v) / sqrtf(1.0f - b2p) + EPSC;
            unew = ucur - (0.1f / (1.0f - b1p)) * m / denom;
            ucur = unew;
        }

        if (t < NSTEPS) {              // nobody consumes u_199 from memory
            if (lane == 0)
                __hip_atomic_store(uout + row, unew, __ATOMIC_RELAXED,
                                   __HIP_MEMORY_SCOPE_AGENT);
            // B2: each wave's s_waitcnt vmcnt(0) before s_barrier drains its
            // u store -> release ordering for the fan-out flags below.
            __syncthreads();

            int* slab = fpriv + (size_t)(t & 1) * NBLK * NBLK;

            // ---- fan-out: tell every consumer "block bid finished t" ----
            if (tid < NBLK)
                __hip_atomic_store(slab + (size_t)tid * NBLK + bid, t,
                                   __ATOMIC_RELAXED, __HIP_MEMORY_SCOPE_AGENT);

            // ---- private poll: sole poller of OUR 8 flag lines ----
            if (tid < 64) {
                const u64* f64 = (const u64*)(slab + (size_t)bid * NBLK);
                const u64 PAIR = ((u64)(unsigned)t << 32) | (unsigned)t;
                int spin = 0;
                for (;;) {
                    u64 a = __hip_atomic_load(f64 + lane,      __ATOMIC_RELAXED, __HIP_MEMORY_SCOPE_AGENT);
                    u64 c = __hip_atomic_load(f64 + lane + 64, __ATOMIC_RELAXED, __HIP_MEMORY_SCOPE_AGENT);
                    if (__all((a == PAIR) & (c == PAIR))) break;
                    if (++spin > (1 << 24)) break;   // fail visibly, never hang
                }
            }
            __syncthreads();           // B3: all 256 producers done -> u_t
                                       // fully visible (r7 lesson: barrier
                                       // between flag observation and load)

            // ---- load u_t segment for next iteration (2x8B, 16 B/lane) ----
            u64 d0 = __hip_atomic_load((const u64*)(uout + col0),     __ATOMIC_RELAXED, __HIP_MEMORY_SCOPE_AGENT);
            u64 d1 = __hip_atomic_load((const u64*)(uout + col0 + 2), __ATOMIC_RELAXED, __HIP_MEMORY_SCOPE_AGENT);
            uv0 = __uint_as_float((unsigned)d0);  uv1 = __uint_as_float((unsigned)(d0 >> 32));
            uv2 = __uint_as_float((unsigned)d1);  uv3 = __uint_as_float((unsigned)(d1 >> 32));
        }
    }

    if (lane == 0) w_out[row] = ucur + mrow;
}

extern "C" void kernel_launch(void* const* d_in, const int* in_sizes, int n_in,
                              void* d_out, int out_size, void* d_ws, size_t ws_size,
                              hipStream_t stream) {
    const float* mean = (const float*)d_in[0];   // (4096,)
    const float* va   = (const float*)d_in[1];   // (4096,4096)
    float* w_out = (float*)d_out;                // (4096,)

    float* ws = (float*)d_ws;
    float* Qs    = ws;                            // 64 MB
    float* u0    = ws + (size_t)MDIM * MDIM;      // 16 KB
    float* u1    = u0 + MDIM;                     // 16 KB
    int*   fpriv = (int*)(u1 + MDIM);             // 2*256*256 ints = 512 KB

    const int nf = 2 * NBLK * NBLK;

    prep_qs<<<dim3(MDIM / 32, MDIM / 32), dim3(32, 8), 0, stream>>>(va, Qs);
    init_state<<<(nf + 255) / 256, 256, 0, stream>>>(mean, u0, fpriv, nf);

    void* args[] = { (void*)&Qs, (void*)&u0, (void*)&u1,
                     (void*)&mean, (void*)&w_out, (void*)&fpriv };
    hipLaunchCooperativeKernel((const void*)adam_persist,
                               dim3(NBLK), dim3(NTHR), args, 0, stream);
}